// Round 5
// baseline (287.077 us; speedup 1.0000x reference)
//
#include <hip/hip_runtime.h>
#include <math.h>

#define D 64
#define S 4

// ---------------- workspace layout (float offsets) ----------------
#define WS_KEYS 0      // keys[S][D]
#define WS_ST   256    // st_norm[S]
#define WS_SUMS 260    // uw_sums[S] (atomic, zeroed each launch)
#define WS_LW   264    // last_writer[S] (int, -1 init)
#define WS_OUT1 272    // out1[D] (16B aligned)
#define WS_WQT  512    // WqT[k][d] = Wq[d][k], 64x64

#define NBLK 1024

__global__ void k_prep(const float* __restrict__ slots,
                       const float* __restrict__ ss,
                       const float* __restrict__ Wk,
                       const float* __restrict__ bk,
                       const float* __restrict__ Wq,
                       float* __restrict__ ws) {
  int d = threadIdx.x;  // 64 threads
  __shared__ float sl[S][D];
  for (int s = 0; s < S; ++s) sl[s][d] = slots[s * D + d];
  __syncthreads();
  float bkd = bk[d];
  for (int s = 0; s < S; ++s) {
    float acc = bkd;
    for (int k = 0; k < D; ++k) acc = fmaf(sl[s][k], Wk[d * D + k], acc);
    ws[WS_KEYS + s * D + d] = tanhf(acc);
  }
  // transpose Wq into ws: WqT[k][d] = Wq[d][k]
  for (int k = 0; k < D; ++k) ws[WS_WQT + k * D + d] = Wq[d * D + k];
  if (d < S) {
    ws[WS_SUMS + d] = 0.f;
    ((int*)ws)[WS_LW + d] = -1;
  }
  if (d == 0) {
    float st[S]; float tot = 0.f;
    for (int s = 0; s < S; ++s) {
      float x = ss[s];
      float sp = log1pf(expf(-fabsf(x))) + fmaxf(x, 0.f);  // softplus
      st[s] = sp; tot += sp;
    }
    for (int s = 0; s < S; ++s) ws[WS_ST + s] = st[s] / tot;
  }
}

// NOTE: macro params must not collide with .x/.y/.z/.w member names
#define FMA4(A_, XS_, W_) \
  A_.x = fmaf(XS_, W_.x, A_.x); A_.y = fmaf(XS_, W_.y, A_.y); \
  A_.z = fmaf(XS_, W_.z, A_.z); A_.w = fmaf(XS_, W_.w, A_.w);

#define TANH1(V_) fmaf(-2.f, __builtin_amdgcn_rcpf(__expf(2.f * (V_)) + 1.f), 1.f)
#define TANH4(A_) { A_.x = TANH1(A_.x); A_.y = TANH1(A_.y); A_.z = TANH1(A_.z); A_.w = TANH1(A_.w); }

#define DOT4(A_, K_) fmaf(A_.w, K_.w, fmaf(A_.z, K_.z, fmaf(A_.y, K_.y, A_.x * K_.x)))

// Cooperative tile kernel: 64 rows/block-tile, thread (rg=t>>4, dg=t&15)
// computes rows [4rg..4rg+4) x dims [4dg..4dg+4).
__launch_bounds__(256)
__global__ void k_main(const float* __restrict__ item,
                       const float* __restrict__ wqt,   // ws+WS_WQT
                       const float* __restrict__ keys,  // ws+WS_KEYS
                       const float* __restrict__ st4,   // ws+WS_ST
                       const float* __restrict__ bq,
                       float* red,                      // ws (atomics)
                       float* __restrict__ slot_weights,
                       float* __restrict__ selected,
                       int B) {
  __shared__ float4 wq4[D * 16];     // wq4[k*16+dq] = WqT[k][4dq..4dq+4)  16KB
  __shared__ float4 xs4[D * 17];     // 64 rows x 17 f4 (68-float padded rows)
  __shared__ float  red_sum[4][S];
  __shared__ int    red_lw[4][S];

  int t = threadIdx.x;
  int rg = t >> 4;   // 0..15 : row group (4 rows)
  int dg = t & 15;   // 0..15 : dim group (4 dims)

  // stage W once per block (linear copy, coalesced both sides)
  for (int i = t; i < D * 16; i += 256) wq4[i] = ((const float4*)wqt)[i];

  // persistent per-thread constants
  float4 bqv = *(const float4*)(bq + 4 * dg);
  float4 kv0 = *(const float4*)(keys + 0 * D + 4 * dg);
  float4 kv1 = *(const float4*)(keys + 1 * D + 4 * dg);
  float4 kv2 = *(const float4*)(keys + 2 * D + 4 * dg);
  float4 kv3 = *(const float4*)(keys + 3 * D + 4 * dg);
  float s0 = st4[0], s1 = st4[1], s2 = st4[2], s3 = st4[3];

  int lane = t & 63, wid = t >> 6;
  int tiles = (B + 63) >> 6;

  for (int tt = blockIdx.x; tt < tiles; tt += NBLK) {
    long row0 = (long)tt << 6;

    __syncthreads();   // xs4 / red arrays free from previous iteration
    {
      const float4* gsrc = (const float4*)item + (row0 << 4);
      #pragma unroll
      for (int i = 0; i < 4; ++i) {
        int idx = t + 256 * i;
        int r = idx >> 4, c4 = idx & 15;
        float4 v = make_float4(0.f, 0.f, 0.f, 0.f);
        if (row0 + r < B) v = gsrc[idx];
        xs4[r * 17 + c4] = v;
      }
    }
    __syncthreads();

    float4 acc0 = bqv, acc1 = bqv, acc2 = bqv, acc3 = bqv;
    int xbase = (4 * rg) * 17;

    #pragma unroll 4
    for (int kq = 0; kq < 16; ++kq) {
      float4 xv0 = xs4[xbase + kq];
      float4 xv1 = xs4[xbase + 17 + kq];
      float4 xv2 = xs4[xbase + 34 + kq];
      float4 xv3 = xs4[xbase + 51 + kq];
      float4 w0 = wq4[(kq * 4 + 0) * 16 + dg];
      float4 w1 = wq4[(kq * 4 + 1) * 16 + dg];
      float4 w2 = wq4[(kq * 4 + 2) * 16 + dg];
      float4 w3 = wq4[(kq * 4 + 3) * 16 + dg];
      FMA4(acc0, xv0.x, w0) FMA4(acc0, xv0.y, w1) FMA4(acc0, xv0.z, w2) FMA4(acc0, xv0.w, w3)
      FMA4(acc1, xv1.x, w0) FMA4(acc1, xv1.y, w1) FMA4(acc1, xv1.z, w2) FMA4(acc1, xv1.w, w3)
      FMA4(acc2, xv2.x, w0) FMA4(acc2, xv2.y, w1) FMA4(acc2, xv2.z, w2) FMA4(acc2, xv2.w, w3)
      FMA4(acc3, xv3.x, w0) FMA4(acc3, xv3.y, w1) FMA4(acc3, xv3.z, w2) FMA4(acc3, xv3.w, w3)
    }

    TANH4(acc0) TANH4(acc1) TANH4(acc2) TANH4(acc3)

    // partial sims p[r*4+s] over this thread's 4 dims
    float p[16];
    p[0]  = DOT4(acc0, kv0); p[1]  = DOT4(acc0, kv1); p[2]  = DOT4(acc0, kv2); p[3]  = DOT4(acc0, kv3);
    p[4]  = DOT4(acc1, kv0); p[5]  = DOT4(acc1, kv1); p[6]  = DOT4(acc1, kv2); p[7]  = DOT4(acc1, kv3);
    p[8]  = DOT4(acc2, kv0); p[9]  = DOT4(acc2, kv1); p[10] = DOT4(acc2, kv2); p[11] = DOT4(acc2, kv3);
    p[12] = DOT4(acc3, kv0); p[13] = DOT4(acc3, kv1); p[14] = DOT4(acc3, kv2); p[15] = DOT4(acc3, kv3);

    // reduce across the 16 dg lanes (xor masks stay within the 16-lane group)
    #pragma unroll
    for (int m = 1; m <= 8; m <<= 1) {
      #pragma unroll
      for (int i = 0; i < 16; ++i) p[i] += __shfl_xor(p[i], m);
    }

    // lane dg<4 handles row 4rg+dg ; select its sims with constant indices
    float q0 = p[0], q1 = p[1], q2 = p[2], q3 = p[3];
    if (dg == 1)      { q0 = p[4];  q1 = p[5];  q2 = p[6];  q3 = p[7];  }
    else if (dg == 2) { q0 = p[8];  q1 = p[9];  q2 = p[10]; q3 = p[11]; }
    else if (dg == 3) { q0 = p[12]; q1 = p[13]; q2 = p[14]; q3 = p[15]; }

    long row = row0 + 4 * rg + dg;
    bool act = (dg < 4) && (row < B);

    float m0 = fmaxf(fmaxf(q0, q1), fmaxf(q2, q3));
    float e0 = expf(q0 - m0), e1 = expf(q1 - m0), e2 = expf(q2 - m0), e3 = expf(q3 - m0);
    float se = e0 + e1 + e2 + e3;
    float w0 = e0 / se, w1 = e1 / se, w2 = e2 / se, w3 = e3 / se;
    if (act) *(float4*)(slot_weights + row * S) = make_float4(w0, w1, w2, w3);

    float u0 = w0 * s0, u1 = w1 * s1, u2 = w2 * s2, u3 = w3 * s3;
    float us = u0 + u1 + u2 + u3;
    u0 /= us; u1 /= us; u2 /= us; u3 /= us;
    int sel = 0;
    float best = u0;
    if (u1 > best) { best = u1; sel = 1; }
    if (u2 > best) { best = u2; sel = 2; }
    if (u3 > best) { best = u3; sel = 3; }
    if (act) selected[row] = (float)sel;

    // block reduction: uw sums (add) + last-writer (max)
    float r4[S]; int l4[S];
    r4[0] = act ? u0 : 0.f; r4[1] = act ? u1 : 0.f;
    r4[2] = act ? u2 : 0.f; r4[3] = act ? u3 : 0.f;
    #pragma unroll
    for (int s = 0; s < S; ++s) l4[s] = (act && sel == s) ? (int)row : -1;
    #pragma unroll
    for (int off = 32; off > 0; off >>= 1) {
      #pragma unroll
      for (int s = 0; s < S; ++s) {
        r4[s] += __shfl_down(r4[s], off);
        int mm = __shfl_down(l4[s], off);
        l4[s] = l4[s] > mm ? l4[s] : mm;
      }
    }
    if (lane == 0) {
      #pragma unroll
      for (int s = 0; s < S; ++s) { red_sum[wid][s] = r4[s]; red_lw[wid][s] = l4[s]; }
    }
    __syncthreads();
    if (t < S) {
      float tot = red_sum[0][t] + red_sum[1][t] + red_sum[2][t] + red_sum[3][t];
      atomicAdd(&red[WS_SUMS + t], tot);
      int lm = red_lw[0][t];
      if (red_lw[1][t] > lm) lm = red_lw[1][t];
      if (red_lw[2][t] > lm) lm = red_lw[2][t];
      if (red_lw[3][t] > lm) lm = red_lw[3][t];
      atomicMax((int*)red + WS_LW + t, lm);
    }
  }
}

__global__ void k_final(const float* __restrict__ item,
                        const float* __restrict__ slots,
                        const float* __restrict__ usage,
                        const float* __restrict__ Wv,
                        const float* __restrict__ bv,
                        float* ws,
                        float* __restrict__ out_ns,
                        float* __restrict__ out_nu,
                        int B) {
  int d = threadIdx.x;  // 64 threads
  __shared__ float mean[D];
  const int* lw = (const int*)ws + WS_LW;
  float nsv[S];
  for (int s = 0; s < S; ++s) {
    int w = lw[s];
    float v = (w >= 0) ? item[(size_t)w * D + d] : slots[s * D + d];
    nsv[s] = v;
    out_ns[s * D + d] = v;
  }
  mean[d] = (nsv[0] + nsv[1] + nsv[2] + nsv[3]) * 0.25f;
  __syncthreads();
  float acc = bv[d];
  for (int k = 0; k < D; ++k) acc = fmaf(mean[k], Wv[d * D + k], acc);
  ws[WS_OUT1 + d] = tanhf(acc);
  if (d < S) out_nu[d] = usage[d] * 0.9f + ws[WS_SUMS + d] / (float)B;
}

__global__ void k_bcast(const float* __restrict__ ws,
                        float4* __restrict__ out, long n4) {
  __shared__ float4 o4[16];
  if (threadIdx.x < 16) o4[threadIdx.x] = ((const float4*)(ws + WS_OUT1))[threadIdx.x];
  __syncthreads();
  long i = (long)blockIdx.x * blockDim.x + threadIdx.x;
  long stride = (long)gridDim.x * blockDim.x;
  for (; i < n4; i += stride) out[i] = o4[i & 15];
}

extern "C" void kernel_launch(void* const* d_in, const int* in_sizes, int n_in,
                              void* d_out, int out_size, void* d_ws, size_t ws_size,
                              hipStream_t stream) {
  const float* item  = (const float*)d_in[0];
  const float* slots = (const float*)d_in[1];
  const float* ss    = (const float*)d_in[2];
  const float* usage = (const float*)d_in[3];
  const float* Wq    = (const float*)d_in[4];
  const float* bq    = (const float*)d_in[5];
  const float* Wk    = (const float*)d_in[6];
  const float* bk    = (const float*)d_in[7];
  const float* Wv    = (const float*)d_in[8];
  const float* bv    = (const float*)d_in[9];
  int B = in_sizes[0] / D;
  float* ws = (float*)d_ws;

  float* out_output       = (float*)d_out;
  float* out_new_slots    = out_output + (size_t)B * D;
  float* out_new_usage    = out_new_slots + S * D;
  float* out_selected     = out_new_usage + S;
  float* out_slot_weights = out_selected + B;

  k_prep<<<1, 64, 0, stream>>>(slots, ss, Wk, bk, Wq, ws);
  k_main<<<NBLK, 256, 0, stream>>>(
      item, ws + WS_WQT, ws + WS_KEYS, ws + WS_ST, bq, ws,
      out_slot_weights, out_selected, B);
  k_final<<<1, 64, 0, stream>>>(item, slots, usage, Wv, bv, ws,
                                out_new_slots, out_new_usage, B);
  long n4 = (long)B * D / 4;
  k_bcast<<<2048, 256, 0, stream>>>(ws, (float4*)out_output, n4);
}

// Round 6
// 183.200 us; speedup vs baseline: 1.5670x; 1.5670x over previous
//
#include <hip/hip_runtime.h>
#include <math.h>

#define D 64
#define S 4

// ---------------- workspace layout (float offsets) ----------------
#define WS_KEYS 0      // keys[S][D]
#define WS_ST   256    // st_norm[S]
#define WS_SUMS 260    // uw_sums[S] (atomic, zeroed each launch)
#define WS_LW   264    // last_writer[S] (int, -1 init)
#define WS_OUT1 272    // out1[D] (16B aligned)
#define WS_WQT  512    // WqT[k][d] = Wq[d][k], 64x64

__global__ void k_prep(const float* __restrict__ slots,
                       const float* __restrict__ ss,
                       const float* __restrict__ Wk,
                       const float* __restrict__ bk,
                       const float* __restrict__ Wq,
                       float* __restrict__ ws) {
  int d = threadIdx.x;  // 64 threads
  __shared__ float sl[S][D];
  for (int s = 0; s < S; ++s) sl[s][d] = slots[s * D + d];
  __syncthreads();
  float bkd = bk[d];
  for (int s = 0; s < S; ++s) {
    float acc = bkd;
    for (int k = 0; k < D; ++k) acc = fmaf(sl[s][k], Wk[d * D + k], acc);
    ws[WS_KEYS + s * D + d] = tanhf(acc);
  }
  // transpose Wq into ws: WqT[k][d] = Wq[d][k]
  for (int k = 0; k < D; ++k) ws[WS_WQT + k * D + d] = Wq[d * D + k];
  if (d < S) {
    ws[WS_SUMS + d] = 0.f;
    ((int*)ws)[WS_LW + d] = -1;
  }
  if (d == 0) {
    float st[S]; float tot = 0.f;
    for (int s = 0; s < S; ++s) {
      float x = ss[s];
      float sp = log1pf(expf(-fabsf(x))) + fmaxf(x, 0.f);  // softplus
      st[s] = sp; tot += sp;
    }
    for (int s = 0; s < S; ++s) ws[WS_ST + s] = st[s] / tot;
  }
}

// NOTE: macro params must not collide with .x/.y/.z/.w member names
#define FMA4(A_, XS_, W_) \
  A_.x = fmaf(XS_, W_.x, A_.x); A_.y = fmaf(XS_, W_.y, A_.y); \
  A_.z = fmaf(XS_, W_.z, A_.z); A_.w = fmaf(XS_, W_.w, A_.w);

#define TANH1(V_) fmaf(-2.f, __builtin_amdgcn_rcpf(__expf(2.f * (V_)) + 1.f), 1.f)
#define TANH4(A_) { A_.x = TANH1(A_.x); A_.y = TANH1(A_.y); A_.z = TANH1(A_.z); A_.w = TANH1(A_.w); }

#define DOT4ACC(P_, A_, K_) \
  P_ = fmaf(A_.x, K_.x, P_); P_ = fmaf(A_.y, K_.y, P_); \
  P_ = fmaf(A_.z, K_.z, P_); P_ = fmaf(A_.w, K_.w, P_);

// one k-scalar step: broadcast XS_ against the full 64-wide W row (16 f4)
#define KSTEP(WP_, XS_) { \
  FMA4(A0,  XS_, WP_[0])  FMA4(A1,  XS_, WP_[1])  FMA4(A2,  XS_, WP_[2])  FMA4(A3,  XS_, WP_[3])  \
  FMA4(A4,  XS_, WP_[4])  FMA4(A5,  XS_, WP_[5])  FMA4(A6,  XS_, WP_[6])  FMA4(A7,  XS_, WP_[7])  \
  FMA4(A8,  XS_, WP_[8])  FMA4(A9,  XS_, WP_[9])  FMA4(A10, XS_, WP_[10]) FMA4(A11, XS_, WP_[11]) \
  FMA4(A12, XS_, WP_[12]) FMA4(A13, XS_, WP_[13]) FMA4(A14, XS_, WP_[14]) FMA4(A15, XS_, WP_[15]) }

// 1 row/lane. W, keys, bq, st wave-uniform -> SGPR operands; acc in 16 NAMED
// float4s (named vars proven spill-free in R5). No LDS in the hot loop.
// B % 256 == 0 -> no tail guards anywhere.
__launch_bounds__(256, 1)
__global__ void k_main(const float* __restrict__ item,
                       const float* __restrict__ wqt,   // ws+WS_WQT
                       const float* __restrict__ keys,  // ws+WS_KEYS
                       const float* __restrict__ st4,   // ws+WS_ST
                       const float* __restrict__ bq,
                       float* red,                      // ws (atomics)
                       float* __restrict__ slot_weights,
                       float* __restrict__ selected,
                       int B) {
  __shared__ float red_sum[4][S];
  __shared__ int   red_lw[4][S];

  int t = threadIdx.x;
  long b = (long)blockIdx.x * 256 + t;

  const float4* bq4 = (const float4*)bq;
  float4 A0  = bq4[0],  A1  = bq4[1],  A2  = bq4[2],  A3  = bq4[3];
  float4 A4  = bq4[4],  A5  = bq4[5],  A6  = bq4[6],  A7  = bq4[7];
  float4 A8  = bq4[8],  A9  = bq4[9],  A10 = bq4[10], A11 = bq4[11];
  float4 A12 = bq4[12], A13 = bq4[13], A14 = bq4[14], A15 = bq4[15];

  const float4* row = (const float4*)(item + b * D);
  const float4* wr  = (const float4*)wqt;    // wr[k*16 + dq], uniform

  float4 iv = row[0];
  #pragma unroll 1
  for (int kk = 0; kk < 16; ++kk) {
    float4 cur = iv;
    if (kk < 15) iv = row[kk + 1];           // uniform-trip prefetch
    const float4* w0 = wr + (kk * 4 + 0) * 16;
    const float4* w1 = wr + (kk * 4 + 1) * 16;
    const float4* w2 = wr + (kk * 4 + 2) * 16;
    const float4* w3 = wr + (kk * 4 + 3) * 16;
    KSTEP(w0, cur.x)
    KSTEP(w1, cur.y)
    KSTEP(w2, cur.z)
    KSTEP(w3, cur.w)
  }

  TANH4(A0)  TANH4(A1)  TANH4(A2)  TANH4(A3)
  TANH4(A4)  TANH4(A5)  TANH4(A6)  TANH4(A7)
  TANH4(A8)  TANH4(A9)  TANH4(A10) TANH4(A11)
  TANH4(A12) TANH4(A13) TANH4(A14) TANH4(A15)

  const float4* kr = (const float4*)keys;    // uniform
  float sim[S];
  #pragma unroll
  for (int s = 0; s < S; ++s) {
    const float4* k4 = kr + s * 16;
    float p = 0.f;
    DOT4ACC(p, A0,  k4[0])  DOT4ACC(p, A1,  k4[1])  DOT4ACC(p, A2,  k4[2])  DOT4ACC(p, A3,  k4[3])
    DOT4ACC(p, A4,  k4[4])  DOT4ACC(p, A5,  k4[5])  DOT4ACC(p, A6,  k4[6])  DOT4ACC(p, A7,  k4[7])
    DOT4ACC(p, A8,  k4[8])  DOT4ACC(p, A9,  k4[9])  DOT4ACC(p, A10, k4[10]) DOT4ACC(p, A11, k4[11])
    DOT4ACC(p, A12, k4[12]) DOT4ACC(p, A13, k4[13]) DOT4ACC(p, A14, k4[14]) DOT4ACC(p, A15, k4[15])
    sim[s] = p;
  }

  float s0 = st4[0], s1 = st4[1], s2 = st4[2], s3 = st4[3];

  float u[S];
  int sel = 0;
  {
    float m = fmaxf(fmaxf(sim[0], sim[1]), fmaxf(sim[2], sim[3]));
    float e0 = expf(sim[0] - m), e1 = expf(sim[1] - m);
    float e2 = expf(sim[2] - m), e3 = expf(sim[3] - m);
    float se = e0 + e1 + e2 + e3;
    float w0 = e0 / se, w1 = e1 / se, w2 = e2 / se, w3 = e3 / se;
    *(float4*)(slot_weights + b * S) = make_float4(w0, w1, w2, w3);
    u[0] = w0 * s0; u[1] = w1 * s1; u[2] = w2 * s2; u[3] = w3 * s3;
    float us = u[0] + u[1] + u[2] + u[3];
    u[0] /= us; u[1] /= us; u[2] /= us; u[3] /= us;
    float best = u[0];
    if (u[1] > best) { best = u[1]; sel = 1; }
    if (u[2] > best) { best = u[2]; sel = 2; }
    if (u[3] > best) { best = u[3]; sel = 3; }
    selected[b] = (float)sel;
  }

  // ---- block reduction: uw sums (add) and last-writer (max) ----
  float r[S]; int l[S];
  #pragma unroll
  for (int s = 0; s < S; ++s) {
    r[s] = u[s];
    l[s] = (sel == s) ? (int)b : -1;
  }
  #pragma unroll
  for (int off = 32; off > 0; off >>= 1) {
    #pragma unroll
    for (int s = 0; s < S; ++s) {
      r[s] += __shfl_down(r[s], off);
      int m = __shfl_down(l[s], off);
      l[s] = l[s] > m ? l[s] : m;
    }
  }
  int lane = t & 63, wid = t >> 6;
  if (lane == 0) {
    #pragma unroll
    for (int s = 0; s < S; ++s) { red_sum[wid][s] = r[s]; red_lw[wid][s] = l[s]; }
  }
  __syncthreads();
  if (t < S) {
    float tot = red_sum[0][t] + red_sum[1][t] + red_sum[2][t] + red_sum[3][t];
    atomicAdd(&red[WS_SUMS + t], tot);
    int lm = red_lw[0][t];
    if (red_lw[1][t] > lm) lm = red_lw[1][t];
    if (red_lw[2][t] > lm) lm = red_lw[2][t];
    if (red_lw[3][t] > lm) lm = red_lw[3][t];
    atomicMax((int*)red + WS_LW + t, lm);
  }
}

__global__ void k_final(const float* __restrict__ item,
                        const float* __restrict__ slots,
                        const float* __restrict__ usage,
                        const float* __restrict__ Wv,
                        const float* __restrict__ bv,
                        float* ws,
                        float* __restrict__ out_ns,
                        float* __restrict__ out_nu,
                        int B) {
  int d = threadIdx.x;  // 64 threads
  __shared__ float mean[D];
  const int* lw = (const int*)ws + WS_LW;
  float nsv[S];
  for (int s = 0; s < S; ++s) {
    int w = lw[s];
    float v = (w >= 0) ? item[(size_t)w * D + d] : slots[s * D + d];
    nsv[s] = v;
    out_ns[s * D + d] = v;
  }
  mean[d] = (nsv[0] + nsv[1] + nsv[2] + nsv[3]) * 0.25f;
  __syncthreads();
  float acc = bv[d];
  for (int k = 0; k < D; ++k) acc = fmaf(mean[k], Wv[d * D + k], acc);
  ws[WS_OUT1 + d] = tanhf(acc);
  if (d < S) out_nu[d] = usage[d] * 0.9f + ws[WS_SUMS + d] / (float)B;
}

__global__ void k_bcast(const float* __restrict__ ws,
                        float4* __restrict__ out, long n4) {
  __shared__ float4 o4[16];
  if (threadIdx.x < 16) o4[threadIdx.x] = ((const float4*)(ws + WS_OUT1))[threadIdx.x];
  __syncthreads();
  long i = (long)blockIdx.x * blockDim.x + threadIdx.x;
  long stride = (long)gridDim.x * blockDim.x;
  for (; i < n4; i += stride) out[i] = o4[i & 15];
}

extern "C" void kernel_launch(void* const* d_in, const int* in_sizes, int n_in,
                              void* d_out, int out_size, void* d_ws, size_t ws_size,
                              hipStream_t stream) {
  const float* item  = (const float*)d_in[0];
  const float* slots = (const float*)d_in[1];
  const float* ss    = (const float*)d_in[2];
  const float* usage = (const float*)d_in[3];
  const float* Wq    = (const float*)d_in[4];
  const float* bq    = (const float*)d_in[5];
  const float* Wk    = (const float*)d_in[6];
  const float* bk    = (const float*)d_in[7];
  const float* Wv    = (const float*)d_in[8];
  const float* bv    = (const float*)d_in[9];
  int B = in_sizes[0] / D;
  float* ws = (float*)d_ws;

  float* out_output       = (float*)d_out;
  float* out_new_slots    = out_output + (size_t)B * D;
  float* out_new_usage    = out_new_slots + S * D;
  float* out_selected     = out_new_usage + S;
  float* out_slot_weights = out_selected + B;

  k_prep<<<1, 64, 0, stream>>>(slots, ss, Wk, bk, Wq, ws);
  k_main<<<(B + 255) / 256, 256, 0, stream>>>(
      item, ws + WS_WQT, ws + WS_KEYS, ws + WS_ST, bq, ws,
      out_slot_weights, out_selected, B);
  k_final<<<1, 64, 0, stream>>>(item, slots, usage, Wv, bv, ws,
                                out_new_slots, out_new_usage, B);
  long n4 = (long)B * D / 4;
  k_bcast<<<2048, 256, 0, stream>>>(ws, (float4*)out_output, n4);
}